// Round 9
// baseline (2602.478 us; speedup 1.0000x reference)
//
#include <hip/hip_runtime.h>
#include <hip/hip_bf16.h>
#include <cstdint>

// Problem constants: B=8, D=512, T=2048, K=8192. BT = 16384 queries.
constexpr int Dv = 512;
constexpr int Tv = 2048;
constexpr int Kv = 8192;
constexpr int BT = 16384;

// vq_main geometry: block = 256 thr = 4 waves. Wave handles 16 q x 64 k
// (k = lane). Block = 64 q x 64 k per chunk; owns KRANGE=1024 k (16 chunks).
constexpr int KSPL = 8;                 // k-splits
constexpr int NBLK = (BT / 64) * KSPL;  // 2048 blocks

// ---------------------------------------------------------------- x_sq ----
__global__ void vq_xsq(const float* __restrict__ lat, float* __restrict__ xsq) {
    int q = blockIdx.x * 256 + threadIdx.x;      // 64 blocks x 256 = 16384
    int b = q >> 11, t = q & 2047;
    const float* p = lat + (size_t)b * Dv * Tv + t;
    float a = 0.f;
    #pragma unroll 8
    for (int d = 0; d < Dv; ++d) {
        float v = p[(size_t)d * Tv];
        a = fmaf(v, v, a);
    }
    xsq[q] = a;
}

// ---------------------------------------------------------------- e_sq ----
__global__ void vq_esq(const float* __restrict__ emb, float* __restrict__ esq) {
    int gid = blockIdx.x * 256 + threadIdx.x;
    int k = gid >> 6;                 // one wave per code row
    int l = threadIdx.x & 63;
    const float* p = emb + (size_t)k * Dv + l;
    float a = 0.f;
    #pragma unroll
    for (int i = 0; i < 8; ++i) {
        float v = p[i * 64];
        a = fmaf(v, v, a);
    }
    #pragma unroll
    for (int off = 32; off; off >>= 1) a += __shfl_down(a, off, 64);
    if (l == 0) esq[k] = a;
}

// ----------------------------------------------------------------- init ---
__global__ void vq_init(unsigned long long* __restrict__ keys) {
    int q = blockIdx.x * 256 + threadIdx.x;
    keys[q] = 0xFFFFFFFFFFFFFFFFull;
}

// ----------------------------------------------------------------- main ---
// k-per-lane: lane l owns code k0+l; wave owns 16 queries; acc[16] regs.
// E tile [64k][32d] in LDS, rows padded to 36 floats (144B): b128-aligned,
// bank-group (row+quad)%8 -> even spread, zero conflict beyond data floor,
// all read offsets are compile-time immediates (no LDS address VALU).
// X is wave-uniform: readfirstlane-derived pointer -> scalar s_load path
// (SMEM pipe, parallel to VALU). acc chain over d is strictly sequential ->
// bit-identical to np reference.
__global__ __launch_bounds__(256, 6) void vq_main(
        const float* __restrict__ lat, const float* __restrict__ emb,
        const float* __restrict__ xsq, const float* __restrict__ esq,
        unsigned long long* __restrict__ keys) {
    __shared__ float Es[64 * 36];                 // 9216 B
    __shared__ unsigned long long bestlds[64];    // per-block running best

    const int tid  = threadIdx.x;
    const int lane = tid & 63;
    const int wid  = __builtin_amdgcn_readfirstlane(tid >> 6);  // wave 0..3
    const int bid  = blockIdx.x;
    const int qg   = bid >> 3;          // 2048 q-groups... (256 groups of 64 q)
    const int sub  = bid & 7;           // k-split
    const int q0   = qg * 64;
    const int b    = q0 >> 11;
    const int t0   = q0 & 2047;
    const int k0base = sub * (Kv / KSPL);   // 1024-k range

    if (tid < 64) bestlds[tid] = 0xFFFFFFFFFFFFFFFFull;

    // wave-uniform X base: this wave's 16 queries are contiguous in t.
    const float* latq = lat + (size_t)b * Dv * Tv + t0 + wid * 16;

    float xsv[16];
    #pragma unroll
    for (int q = 0; q < 16; ++q) xsv[q] = xsq[q0 + wid * 16 + q];

    const int srow  = tid >> 3;   // 0..31  (staging row)
    const int squad = tid & 7;    // 0..7   (staging d-quad)

    for (int kc = 0; kc < 16; ++kc) {
        const int k0 = k0base + kc * 64;
        const float esl = esq[k0 + lane];   // per-lane e_sq
        float acc[16];
        #pragma unroll
        for (int q = 0; q < 16; ++q) acc[q] = 0.f;

        for (int dc = 0; dc < 16; ++dc) {
            __syncthreads();
            // stage E chunk [64k][32d]: emb rows are contiguous in d -> no
            // transpose. 8 threads per row read 128B contiguous.
            {
                const float4 v0 = *(const float4*)(emb + (size_t)(k0 + srow) * Dv + dc * 32 + squad * 4);
                const float4 v1 = *(const float4*)(emb + (size_t)(k0 + srow + 32) * Dv + dc * 32 + squad * 4);
                *(float4*)&Es[srow * 36 + squad * 4] = v0;
                *(float4*)&Es[(srow + 32) * 36 + squad * 4] = v1;
            }
            __syncthreads();

            const float4* erow = (const float4*)&Es[lane * 36];
            #pragma unroll
            for (int j = 0; j < 8; ++j) {
                const float4 e4 = erow[j];   // E[lane][4 d's], offset imm j*16
                const float* xj = latq + (size_t)(dc * 32 + j * 4) * Tv;
                const float4* x0 = (const float4*)(xj);
                const float4* x1 = (const float4*)(xj + Tv);
                const float4* x2 = (const float4*)(xj + 2 * (size_t)Tv);
                const float4* x3 = (const float4*)(xj + 3 * (size_t)Tv);
                // STRICTLY sequential fp32 fma chain over d per (q,k):
                // dd order = dc asc, j asc, c asc  == d = 0..511.
                #define VQ_C(EC, XP) { \
                    const float4 xa_ = (XP)[0], xb_ = (XP)[1], xc_ = (XP)[2], xd_ = (XP)[3]; \
                    acc[0]  = fmaf(xa_.x, (EC), acc[0]);  acc[1]  = fmaf(xa_.y, (EC), acc[1]);  \
                    acc[2]  = fmaf(xa_.z, (EC), acc[2]);  acc[3]  = fmaf(xa_.w, (EC), acc[3]);  \
                    acc[4]  = fmaf(xb_.x, (EC), acc[4]);  acc[5]  = fmaf(xb_.y, (EC), acc[5]);  \
                    acc[6]  = fmaf(xb_.z, (EC), acc[6]);  acc[7]  = fmaf(xb_.w, (EC), acc[7]);  \
                    acc[8]  = fmaf(xc_.x, (EC), acc[8]);  acc[9]  = fmaf(xc_.y, (EC), acc[9]);  \
                    acc[10] = fmaf(xc_.z, (EC), acc[10]); acc[11] = fmaf(xc_.w, (EC), acc[11]); \
                    acc[12] = fmaf(xd_.x, (EC), acc[12]); acc[13] = fmaf(xd_.y, (EC), acc[13]); \
                    acc[14] = fmaf(xd_.z, (EC), acc[14]); acc[15] = fmaf(xd_.w, (EC), acc[15]); }
                VQ_C(e4.x, x0)
                VQ_C(e4.y, x1)
                VQ_C(e4.z, x2)
                VQ_C(e4.w, x3)
                #undef VQ_C
            }
        }

        // dist = fl(fl(xs - 2c) + es); pack (dist,k) u64 -> lexicographic
        // min == np.argmin first-index rule (dist ~512 > 0, bits monotone).
        #pragma unroll
        for (int q = 0; q < 16; ++q) {
            float dist = fmaf(-2.0f, acc[q], xsv[q]) + esl;
            unsigned long long key =
                ((unsigned long long)__float_as_uint(dist) << 32)
                | (unsigned int)(k0 + lane);
            #pragma unroll
            for (int off = 32; off; off >>= 1) {
                unsigned long long o = __shfl_xor(key, off, 64);
                key = (o < key) ? o : key;
            }
            if (lane == 0) {
                if (key < bestlds[wid * 16 + q]) bestlds[wid * 16 + q] = key;
            }
        }
    }

    __syncthreads();
    if (tid < 64) atomicMin(&keys[q0 + tid], bestlds[tid]);
}

// --------------------------------------------------------------- gather ---
// out[b][d][t] = emb[idx[b*T+t]][d]; lanes along t -> coalesced stores.
__global__ void vq_gather(const float* __restrict__ emb,
                          const unsigned long long* __restrict__ keys,
                          float* __restrict__ out) {
    int blk = blockIdx.x;            // 256 blocks of 64 queries
    int tid = threadIdx.x;
    int tl = tid & 63, dg = tid >> 6;   // dg in [0,4)
    int q = blk * 64 + tl;
    int b = q >> 11, t = q & 2047;
    int idx = (int)(keys[q] & 0xFFFFFFFFull);
    const float* er = emb + (size_t)idx * Dv + dg * 128;
    float* ob = out + ((size_t)b * Dv + dg * 128) * Tv + t;
    #pragma unroll 8
    for (int i = 0; i < 128; ++i) ob[(size_t)i * Tv] = er[i];
}

// ---------------------------------------------------------------------------
extern "C" void kernel_launch(void* const* d_in, const int* in_sizes, int n_in,
                              void* d_out, int out_size, void* d_ws, size_t ws_size,
                              hipStream_t stream) {
    (void)in_sizes; (void)n_in; (void)out_size; (void)ws_size;
    const float* lat = (const float*)d_in[0];   // [8, 512, 2048]
    const float* emb = (const float*)d_in[1];   // [8192, 512]
    float* out = (float*)d_out;                 // [8, 512, 2048]

    char* ws = (char*)d_ws;
    float* xsq = (float*)(ws);                                   // 64 KB
    float* esq = (float*)(ws + (64 << 10));                      // 32 KB
    unsigned long long* keys =
        (unsigned long long*)(ws + (96 << 10));                  // 128 KB

    vq_init <<<BT / 256, 256, 0, stream>>>(keys);
    vq_xsq  <<<BT / 256, 256, 0, stream>>>(lat, xsq);
    vq_esq  <<<Kv / 4,   256, 0, stream>>>(emb, esq);
    vq_main <<<NBLK, 256, 0, stream>>>(lat, emb, xsq, esq, keys);
    vq_gather<<<BT / 64, 256, 0, stream>>>(emb, keys, out);
}